// Round 1
// baseline (1124.660 us; speedup 1.0000x reference)
//
#include <hip/hip_runtime.h>
#include <stdint.h>

#define THREADS 512
#define NBLOCKS 8192
#define BR      128

// d_ws layout (all bf16, transposed [n][k], chunked, pre-swizzled)
#define WS_WIN   0
#define WS_WHID  32768
#define WS_WOUT  (32768 + 786432)
#define WS_TOTAL (WS_WOUT + 16384)

// LDS layout
#define LDS_W     65536                // act: [128 rows][512 B]
#define LDS_BIAS  (65536 + 65536)      // wbuf: 2 x 32 KB
#define LDS_TOTAL (LDS_BIAS + 7296)    // bias: 1824 f32

typedef short bf16x8  __attribute__((ext_vector_type(8)));
typedef float f32x16  __attribute__((ext_vector_type(16)));
typedef float f32x4v  __attribute__((ext_vector_type(4)));

__device__ __forceinline__ unsigned short f2bf(float f) {
    union { float f; unsigned int u; } v; v.f = f;
    unsigned int u = v.u;
    u += 0x7fffu + ((u >> 16) & 1u);   // round-to-nearest-even
    return (unsigned short)(u >> 16);
}
__device__ __forceinline__ unsigned int pack2(float a, float b) {
    return (unsigned int)f2bf(a) | ((unsigned int)f2bf(b) << 16);
}

typedef const __attribute__((address_space(1))) unsigned int gas_u32;
typedef __attribute__((address_space(3))) unsigned int las_u32;

__device__ __forceinline__ void gload16(const void* g, void* l) {
    __builtin_amdgcn_global_load_lds((gas_u32*)(uintptr_t)g,
                                     (las_u32*)(unsigned int)(uintptr_t)l,
                                     16, 0, 0);
}

// ---------------------------------------------------------------------------
// prep: fp32 weights -> bf16, transposed to [n][k], K-chunked (64), XOR-swizzled
// ---------------------------------------------------------------------------
__global__ void prep_kernel(const float* __restrict__ W_in,
                            const float* __restrict__ W_hid,
                            const float* __restrict__ W_out,
                            unsigned char* __restrict__ ws) {
    int id = blockIdx.x * 256 + threadIdx.x;
    if (id < 16384) {                       // W_in: [40->64 pad][256] -> Wt[256][64]
        int n = id & 255, k = id >> 8;      // k < 64
        float v = (k < 40) ? W_in[k * 256 + n] : 0.f;
        unsigned off = (unsigned)(n * 128) + (((unsigned)(k * 2)) ^ ((n & 7) << 4));
        *(unsigned short*)(ws + WS_WIN + off) = f2bf(v);
    } else if (id < 16384 + 393216) {       // W_hid: 6 layers x 4 chunks x [256][64]
        int e  = id - 16384;
        int lc = e >> 14;                   // l*4 + c, 0..23
        int r  = e & 16383;
        int n  = r & 255, kk = r >> 8;      // kk < 64
        int l = lc >> 2, c = lc & 3;
        float v = W_hid[l * 65536 + (c * 64 + kk) * 256 + n];
        unsigned off = (unsigned)(n * 128) + (((unsigned)(kk * 2)) ^ ((n & 7) << 4));
        *(unsigned short*)(ws + WS_WHID + lc * 32768 + off) = f2bf(v);
    } else if (id < 16384 + 393216 + 8192) { // W_out: [3->32 pad][256]
        int e = id - 16384 - 393216;
        int k = e & 255, n = e >> 8;        // n < 32
        float v = (n < 3) ? W_out[k * 3 + n] : 0.f;
        unsigned off = (unsigned)(n * 512) + (((unsigned)(k * 2)) ^ ((n & 7) << 4));
        *(unsigned short*)(ws + WS_WOUT + off) = f2bf(v);
    }
}

// ---------------------------------------------------------------------------
// fused MLP: enc -> 7x(GEMM+bias+relu) in LDS -> GEMM+bias -> tanh/100 -> out
// ---------------------------------------------------------------------------
__global__ __launch_bounds__(THREADS, 2)
void nerf_main(const float* __restrict__ x,
               const float* __restrict__ b_in,
               const float* __restrict__ b_hid,
               const float* __restrict__ b_out,
               const unsigned char* __restrict__ ws,
               float* __restrict__ out) {
    __shared__ __align__(16) unsigned char smem[LDS_TOTAL];

    const int tid  = threadIdx.x;
    const int lane = tid & 63;
    const int wv   = tid >> 6;            // 0..7
    const int l31  = lane & 31;
    const int hi   = lane >> 5;           // 0/1
    const int hi16 = hi << 4;
    const int swz  = (l31 & 7) << 4;      // XOR bank swizzle (G4)
    const int nblk = (wv & 3) * 64;       // wave's 64 output-neuron slice
    const int rblk = (wv >> 2) * 64;      // wave's 64 batch-row slice
    const long gr0 = (long)blockIdx.x * BR;

    unsigned char* actL  = smem;          // bf16 [128][256], row stride 512 B
    unsigned char* wb0   = smem + LDS_W;  // 2 x 32 KB weight chunks
    float*         biasL = (float*)(smem + LDS_BIAS);

    // ---- prologue: issue x load, bias loads, then stage0 (keeps stage0 async) ----
    const int rr = tid >> 2, part = tid & 3;
    const int co = part >> 1, hf = part & 1;
    float xv = x[(gr0 + rr) * 2 + co];

    float bias_v[4];
    #pragma unroll
    for (int i = 0; i < 4; ++i) {
        int idx = tid + i * THREADS;
        float v = 0.f;
        if (idx < 256) v = b_in[idx];
        else if (idx < 1792) v = b_hid[idx - 256];
        else if (idx < 1795) v = b_out[idx - 1792];
        bias_v[i] = v;
    }

    {   // stage 0: W_in chunk (32 KB) into wbuf[0]
        const unsigned char* g = ws + WS_WIN;
        #pragma unroll
        for (int p = 0; p < 4; ++p)
            gload16(g + p * 8192 + (wv << 10) + (lane << 4),
                    wb0 + p * 8192 + (wv << 10));
    }

    // ---- positional encoding into act LDS (k 0..39, zeros 40..63) ----
    {
        unsigned char* rowp = actL + rr * 512;
        const int rsw = (rr & 7) << 4;
        const int kb = co * 20 + hf * 10;
        float vv[10];
        #pragma unroll
        for (int f = 0; f < 10; ++f) {
            float ang = xv * (float)(1 << f);
            vv[f] = hf ? __cosf(ang) : __sinf(ang);
        }
        #pragma unroll
        for (int p = 0; p < 5; ++p) {
            unsigned int u = pack2(vv[2 * p], vv[2 * p + 1]);
            int byte = (kb + 2 * p) * 2;
            *(unsigned int*)(rowp + (byte ^ rsw)) = u;
        }
        int z = 80 + part * 12;           // zero-pad bytes [80,128)
        *(unsigned int*)(rowp + ((z    ) ^ rsw)) = 0u;
        *(unsigned int*)(rowp + ((z + 4) ^ rsw)) = 0u;
        *(unsigned int*)(rowp + ((z + 8) ^ rsw)) = 0u;
    }
    #pragma unroll
    for (int i = 0; i < 4; ++i) {
        int idx = tid + i * THREADS;
        if (idx < 1824) biasL[idx] = bias_v[i];
    }

    f32x16 acc[2][2];

    // ---- 25 staged chunks: layer0 (1), layers1..6 (4 each) ----
    #pragma unroll 1
    for (int s = 0; s < 25; ++s) {
        const int layer = (s == 0) ? 0 : 1 + ((s - 1) >> 2);
        const int c     = (s == 0) ? 0 : ((s - 1) & 3);

        // B1: prior LDS traffic visible; safe to overwrite wbuf[(s+1)&1]
        asm volatile("s_waitcnt lgkmcnt(0)" ::: "memory");
        __builtin_amdgcn_s_barrier();
        asm volatile("" ::: "memory");

        // issue next stage (async, stays in flight across barrier)
        {
            const int ns = s + 1;
            if (ns < 25) {
                const unsigned char* g = ws + WS_WHID + (ns - 1) * 32768;
                unsigned char* lb = wb0 + (ns & 1) * 32768;
                #pragma unroll
                for (int p = 0; p < 4; ++p)
                    gload16(g + p * 8192 + (wv << 10) + (lane << 4),
                            lb + p * 8192 + (wv << 10));
            } else {
                const unsigned char* g = ws + WS_WOUT;
                unsigned char* lb = wb0 + 32768;
                #pragma unroll
                for (int p = 0; p < 2; ++p)
                    gload16(g + p * 8192 + (wv << 10) + (lane << 4),
                            lb + p * 8192 + (wv << 10));
            }
        }
        if (s + 1 == 25) asm volatile("s_waitcnt vmcnt(2)" ::: "memory");
        else             asm volatile("s_waitcnt vmcnt(4)" ::: "memory");
        __builtin_amdgcn_s_barrier();
        asm volatile("" ::: "memory");

        // bias -> accumulator init at layer start
        if (c == 0) {
            const float* bl = biasL + layer * 256;
            #pragma unroll
            for (int tn = 0; tn < 2; ++tn) {
                #pragma unroll
                for (int g4 = 0; g4 < 4; ++g4) {
                    f32x4v bv = *(const f32x4v*)(bl + nblk + tn * 32 + g4 * 8 + hi * 4);
                    #pragma unroll
                    for (int j = 0; j < 4; ++j) {
                        acc[tn][0][g4 * 4 + j] = bv[j];
                        acc[tn][1][g4 * 4 + j] = bv[j];
                    }
                }
            }
        }

        // compute: 4 K-steps x 4 MFMAs (D[n][r] = Wt x act)
        const unsigned char* wb = wb0 + (s & 1) * 32768;
        #pragma unroll
        for (int kk = 0; kk < 4; ++kk) {
            const int io = ((kk * 32 + hi16) ^ swz);
            bf16x8 a0  = *(const bf16x8*)(wb + (nblk      + l31) * 128 + io);
            bf16x8 a1  = *(const bf16x8*)(wb + (nblk + 32 + l31) * 128 + io);
            bf16x8 bb0 = *(const bf16x8*)(actL + (rblk      + l31) * 512 + c * 128 + io);
            bf16x8 bb1 = *(const bf16x8*)(actL + (rblk + 32 + l31) * 512 + c * 128 + io);
            acc[0][0] = __builtin_amdgcn_mfma_f32_32x32x16_bf16(a0, bb0, acc[0][0], 0, 0, 0);
            acc[1][0] = __builtin_amdgcn_mfma_f32_32x32x16_bf16(a1, bb0, acc[1][0], 0, 0, 0);
            acc[0][1] = __builtin_amdgcn_mfma_f32_32x32x16_bf16(a0, bb1, acc[0][1], 0, 0, 0);
            acc[1][1] = __builtin_amdgcn_mfma_f32_32x32x16_bf16(a1, bb1, acc[1][1], 0, 0, 0);
        }

        // layer end: relu + bf16 pack + write activations back
        if (s == 0 || c == 3) {
            asm volatile("" ::: "memory");
            __builtin_amdgcn_s_barrier();      // all waves done reading act
            asm volatile("" ::: "memory");
            #pragma unroll
            for (int tr = 0; tr < 2; ++tr) {
                unsigned char* rowp = actL + (rblk + tr * 32 + l31) * 512;
                #pragma unroll
                for (int tn = 0; tn < 2; ++tn) {
                    #pragma unroll
                    for (int g4 = 0; g4 < 4; ++g4) {
                        float v0 = fmaxf(acc[tn][tr][g4 * 4 + 0], 0.f);
                        float v1 = fmaxf(acc[tn][tr][g4 * 4 + 1], 0.f);
                        float v2 = fmaxf(acc[tn][tr][g4 * 4 + 2], 0.f);
                        float v3 = fmaxf(acc[tn][tr][g4 * 4 + 3], 0.f);
                        int n0 = nblk + tn * 32 + g4 * 8 + hi * 4;
                        uint2 u; u.x = pack2(v0, v1); u.y = pack2(v2, v3);
                        *(uint2*)(rowp + ((n0 * 2) ^ swz)) = u;
                    }
                }
            }
        }
    }

    // ---- layer 7: [128][256] @ Wt_out[32pad][256] -> tanh/100 -> out ----
    asm volatile("s_waitcnt vmcnt(0)" ::: "memory");
    asm volatile("s_waitcnt lgkmcnt(0)" ::: "memory");
    __builtin_amdgcn_s_barrier();
    asm volatile("" ::: "memory");

    if (wv < 4) {
        const unsigned char* wo = wb0 + 32768;
        f32x16 c0, c1;
        {
            const float* bl = biasL + 1792;
            #pragma unroll
            for (int g4 = 0; g4 < 4; ++g4) {
                f32x4v bv = *(const f32x4v*)(bl + g4 * 8 + hi * 4);
                #pragma unroll
                for (int j = 0; j < 4; ++j) { c0[g4 * 4 + j] = bv[j]; c1[g4 * 4 + j] = 0.f; }
            }
        }
        const unsigned char* arow = actL + (wv * 32 + l31) * 512;
        const unsigned char* wrow = wo + l31 * 512;
        #pragma unroll
        for (int kk = 0; kk < 16; ++kk) {
            const int io = ((kk * 32 + hi16) ^ swz);
            bf16x8 a = *(const bf16x8*)(wrow + io);
            bf16x8 b = *(const bf16x8*)(arow + io);
            if (kk & 1) c1 = __builtin_amdgcn_mfma_f32_32x32x16_bf16(a, b, c1, 0, 0, 0);
            else        c0 = __builtin_amdgcn_mfma_f32_32x32x16_bf16(a, b, c0, 0, 0, 0);
        }
        if (hi == 0) {
            long row = gr0 + wv * 32 + l31;
            float* op = out + row * 3;
            #pragma unroll
            for (int j = 0; j < 3; ++j) {
                float v = c0[j] + c1[j];
                op[j] = tanhf(v) * 0.01f;
            }
        }
    }
}

extern "C" void kernel_launch(void* const* d_in, const int* in_sizes, int n_in,
                              void* d_out, int out_size, void* d_ws, size_t ws_size,
                              hipStream_t stream) {
    (void)in_sizes; (void)n_in; (void)out_size;
    const float* x     = (const float*)d_in[0];
    const float* W_in  = (const float*)d_in[1];
    const float* b_in  = (const float*)d_in[2];
    const float* W_hid = (const float*)d_in[3];
    const float* b_hid = (const float*)d_in[4];
    const float* W_out = (const float*)d_in[5];
    const float* b_out = (const float*)d_in[6];
    unsigned char* ws  = (unsigned char*)d_ws;
    float* out = (float*)d_out;

    if (ws_size < (size_t)WS_TOTAL) return;  // scratch too small: fail loudly (zero output)

    prep_kernel<<<1632, 256, 0, stream>>>(W_in, W_hid, W_out, ws);
    nerf_main<<<NBLOCKS, THREADS, 0, stream>>>(x, b_in, b_hid, b_out, ws, out);
}

// Round 2
// 881.845 us; speedup vs baseline: 1.2753x; 1.2753x over previous
//
#include <hip/hip_runtime.h>
#include <stdint.h>

#define THREADS 512
#define NBLOCKS 8192
#define BR      128

// d_ws layout: bf16 weights re-packed as MFMA A-fragments.
// Fragment = 1KB: 64 lanes x 16B; lane (hi*32+l31) holds rows n=f*32+l31,
// k = kk*16 + hi*8 + e (e=0..7). Frag index within a layer: ((c*4+kk)*8 + f).
#define WS_WIN   0                       // layer0: 1 chunk  -> 4kk*8f KB = 32KB
#define WS_WHID  32768                   // 6 layers x 4c*4kk*8f KB = 128KB each
#define WS_WOUT  (32768 + 786432)        // layer7: 16 kk x 1 frag = 16KB
#define WS_TOTAL (WS_WOUT + 16384)

typedef short bf16x8 __attribute__((ext_vector_type(8)));
typedef float f32x16 __attribute__((ext_vector_type(16)));
typedef float f32x4v __attribute__((ext_vector_type(4)));

__device__ __forceinline__ unsigned short f2bf(float f) {
    union { float f; unsigned int u; } v; v.f = f;
    unsigned int u = v.u;
    u += 0x7fffu + ((u >> 16) & 1u);   // round-to-nearest-even
    return (unsigned short)(u >> 16);
}
__device__ __forceinline__ unsigned int pack2(float a, float b) {
    return (unsigned int)f2bf(a) | ((unsigned int)f2bf(b) << 16);
}

// ---------------------------------------------------------------------------
// prep: fp32 weights -> bf16 MFMA A-fragment layout in ws
// ---------------------------------------------------------------------------
__global__ void prep_kernel(const float* __restrict__ W_in,
                            const float* __restrict__ W_hid,
                            const float* __restrict__ W_out,
                            unsigned char* __restrict__ ws) {
    int id = blockIdx.x * 256 + threadIdx.x;
    if (id < 16384) {                        // W_in: k(64 pad) x n(256)
        int n = id & 255, k = id >> 8;
        int f = n >> 5, ln = n & 31;
        int kk = k >> 4, hi = (k >> 3) & 1, e = k & 7;
        float v = (k < 40) ? W_in[k * 256 + n] : 0.f;
        *(unsigned short*)(ws + WS_WIN + (kk * 8 + f) * 1024
                           + (hi * 32 + ln) * 16 + e * 2) = f2bf(v);
    } else if (id < 16384 + 393216) {        // W_hid: 6 x k(256) x n(256)
        int e2 = id - 16384;
        int l = e2 >> 16, r = e2 & 65535;
        int k = r >> 8, n = r & 255;
        int c = k >> 6, kk = (k >> 4) & 3, hi = (k >> 3) & 1, e = k & 7;
        int f = n >> 5, ln = n & 31;
        float v = W_hid[l * 65536 + k * 256 + n];
        *(unsigned short*)(ws + WS_WHID + l * 131072
                           + ((c * 4 + kk) * 8 + f) * 1024
                           + (hi * 32 + ln) * 16 + e * 2) = f2bf(v);
    } else if (id < 16384 + 393216 + 8192) { // W_out: k(256) x n(3 -> 32 pad)
        int e3 = id - 16384 - 393216;
        int n = e3 >> 8, k = e3 & 255;
        int kk = k >> 4, hi = (k >> 3) & 1, e = k & 7;
        float v = (n < 3) ? W_out[k * 3 + n] : 0.f;
        *(unsigned short*)(ws + WS_WOUT + kk * 1024
                           + (hi * 32 + n) * 16 + e * 2) = f2bf(v);
    }
}

// ---------------------------------------------------------------------------
// one layer: acc = bias; acc += Wt(global frags) x act(LDS); relu; write act
// ---------------------------------------------------------------------------
template <int NC>
__device__ __forceinline__ void layer_pass(const unsigned char* __restrict__ wl,
                                           const float* __restrict__ bp,
                                           unsigned char* actL, f32x16 (&acc)[2][2],
                                           int nblk, int rblk, int l31,
                                           int hi, int hi16, int swz) {
    // bias -> accumulator init (C/D layout: n = (reg&3) + 8*(reg>>2) + 4*hi)
    #pragma unroll
    for (int tn = 0; tn < 2; ++tn) {
        #pragma unroll
        for (int g4 = 0; g4 < 4; ++g4) {
            f32x4v bv = *(const f32x4v*)(bp + nblk + tn * 32 + g4 * 8 + hi * 4);
            #pragma unroll
            for (int j = 0; j < 4; ++j) {
                acc[tn][0][g4 * 4 + j] = bv[j];
                acc[tn][1][g4 * 4 + j] = bv[j];
            }
        }
    }
    const unsigned char* br0 = actL + (rblk      + l31) * 512;
    const unsigned char* br1 = actL + (rblk + 32 + l31) * 512;
    #pragma unroll
    for (int c = 0; c < NC; ++c) {
        #pragma unroll
        for (int kk = 0; kk < 4; ++kk) {
            const unsigned char* fp = wl + (c * 4 + kk) * 8192;
            bf16x8 a0 = *(const bf16x8*)(fp);
            bf16x8 a1 = *(const bf16x8*)(fp + 1024);
            const int io = c * 128 + ((kk * 32 + hi16) ^ swz);
            bf16x8 b0 = *(const bf16x8*)(br0 + io);
            bf16x8 b1 = *(const bf16x8*)(br1 + io);
            acc[0][0] = __builtin_amdgcn_mfma_f32_32x32x16_bf16(a0, b0, acc[0][0], 0, 0, 0);
            acc[1][0] = __builtin_amdgcn_mfma_f32_32x32x16_bf16(a1, b0, acc[1][0], 0, 0, 0);
            acc[0][1] = __builtin_amdgcn_mfma_f32_32x32x16_bf16(a0, b1, acc[0][1], 0, 0, 0);
            acc[1][1] = __builtin_amdgcn_mfma_f32_32x32x16_bf16(a1, b1, acc[1][1], 0, 0, 0);
        }
    }
    __syncthreads();   // all waves done READING act
    #pragma unroll
    for (int tr = 0; tr < 2; ++tr) {
        unsigned char* rowp = actL + (rblk + tr * 32 + l31) * 512;
        #pragma unroll
        for (int tn = 0; tn < 2; ++tn) {
            #pragma unroll
            for (int g4 = 0; g4 < 4; ++g4) {
                float v0 = fmaxf(acc[tn][tr][g4 * 4 + 0], 0.f);
                float v1 = fmaxf(acc[tn][tr][g4 * 4 + 1], 0.f);
                float v2 = fmaxf(acc[tn][tr][g4 * 4 + 2], 0.f);
                float v3 = fmaxf(acc[tn][tr][g4 * 4 + 3], 0.f);
                int n0b = (nblk + tn * 32 + g4 * 8 + hi * 4) * 2;
                uint2 u; u.x = pack2(v0, v1); u.y = pack2(v2, v3);
                *(uint2*)(rowp + (n0b ^ swz)) = u;
            }
        }
    }
    __syncthreads();   // act ready for next layer
}

// ---------------------------------------------------------------------------
// fused MLP: enc -> 7x(GEMM+bias+relu), act in LDS, weights global->reg
// ---------------------------------------------------------------------------
__global__ __launch_bounds__(THREADS, 4)
void nerf_main(const float* __restrict__ x,
               const float* __restrict__ b_in,
               const float* __restrict__ b_hid,
               const float* __restrict__ b_out,
               const unsigned char* __restrict__ ws,
               float* __restrict__ out) {
    __shared__ __align__(16) unsigned char actL[65536];  // bf16 [128][256]

    const int tid  = threadIdx.x;
    const int lane = tid & 63;
    const int wv   = tid >> 6;            // 0..7
    const int l31  = lane & 31;
    const int hi   = lane >> 5;
    const int hi16 = hi << 4;
    const int swz  = (l31 & 7) << 4;      // XOR bank swizzle
    const int ng   = wv & 3,  nblk = ng * 64;
    const int rg   = wv >> 2, rblk = rg * 64;
    const long gr0 = (long)blockIdx.x * BR;

    // ---- positional encoding into act LDS (k 0..39, zeros 40..63) ----
    {
        const int rr = tid >> 2, part = tid & 3;
        const int co = part >> 1, hf = part & 1;
        float xv = x[(gr0 + rr) * 2 + co];
        unsigned char* rowp = actL + rr * 512;
        const int rsw = (rr & 7) << 4;
        const int kb = co * 20 + hf * 10;
        float vv[10];
        #pragma unroll
        for (int f = 0; f < 10; ++f) {
            float ang = xv * (float)(1 << f);
            vv[f] = hf ? __cosf(ang) : __sinf(ang);
        }
        #pragma unroll
        for (int p = 0; p < 5; ++p) {
            unsigned int u = pack2(vv[2 * p], vv[2 * p + 1]);
            int byte = (kb + 2 * p) * 2;
            *(unsigned int*)(rowp + (byte ^ rsw)) = u;
        }
        int z = 80 + part * 12;           // zero-pad bytes [80,128)
        *(unsigned int*)(rowp + ((z    ) ^ rsw)) = 0u;
        *(unsigned int*)(rowp + ((z + 4) ^ rsw)) = 0u;
        *(unsigned int*)(rowp + ((z + 8) ^ rsw)) = 0u;
    }
    __syncthreads();

    f32x16 acc[2][2];

    // layer 0 (k=64, 1 chunk)
    layer_pass<1>(ws + WS_WIN + ng * 2048 + lane * 16, b_in,
                  actL, acc, nblk, rblk, l31, hi, hi16, swz);

    // layers 1..6
    #pragma unroll 1
    for (int l = 0; l < 6; ++l) {
        layer_pass<4>(ws + WS_WHID + l * 131072 + ng * 2048 + lane * 16,
                      b_hid + l * 256,
                      actL, acc, nblk, rblk, l31, hi, hi16, swz);
    }

    // ---- layer 7: [128][256] @ Wt_out[32pad][256] -> tanh/100 -> out ----
    if (wv < 4) {
        f32x16 c0, c1;
        #pragma unroll
        for (int j = 0; j < 16; ++j) { c0[j] = 0.f; c1[j] = 0.f; }
        const unsigned char* wo   = ws + WS_WOUT + lane * 16;
        const unsigned char* arow = actL + (wv * 32 + l31) * 512;
        #pragma unroll
        for (int kk = 0; kk < 16; ++kk) {
            bf16x8 a = *(const bf16x8*)(wo + kk * 1024);
            bf16x8 b = *(const bf16x8*)(arow + (((kk * 32 + hi16)) ^ swz));
            if (kk & 1) c1 = __builtin_amdgcn_mfma_f32_32x32x16_bf16(a, b, c1, 0, 0, 0);
            else        c0 = __builtin_amdgcn_mfma_f32_32x32x16_bf16(a, b, c0, 0, 0, 0);
        }
        if (hi == 0) {
            long row = gr0 + wv * 32 + l31;
            float* op = out + row * 3;
            #pragma unroll
            for (int j = 0; j < 3; ++j)
                op[j] = tanhf(c0[j] + c1[j] + b_out[j]) * 0.01f;
        }
    }
}

extern "C" void kernel_launch(void* const* d_in, const int* in_sizes, int n_in,
                              void* d_out, int out_size, void* d_ws, size_t ws_size,
                              hipStream_t stream) {
    (void)in_sizes; (void)n_in; (void)out_size;
    const float* x     = (const float*)d_in[0];
    const float* W_in  = (const float*)d_in[1];
    const float* b_in  = (const float*)d_in[2];
    const float* W_hid = (const float*)d_in[3];
    const float* b_hid = (const float*)d_in[4];
    const float* W_out = (const float*)d_in[5];
    const float* b_out = (const float*)d_in[6];
    unsigned char* ws  = (unsigned char*)d_ws;
    float* out = (float*)d_out;

    if (ws_size < (size_t)WS_TOTAL) return;

    prep_kernel<<<1632, 256, 0, stream>>>(W_in, W_hid, W_out, ws);
    nerf_main<<<NBLOCKS, THREADS, 0, stream>>>(x, b_in, b_hid, b_out, ws, out);
}

// Round 3
// 818.507 us; speedup vs baseline: 1.3740x; 1.0774x over previous
//
#include <hip/hip_runtime.h>
#include <stdint.h>

#define THREADS 512
#define NBLOCKS 8192
#define BR      128

// d_ws layout: bf16 weights as MFMA A-fragments, CONTIGUOUS per wave (ng).
// Per-ng stream (200KB): [layer0: 8KB][layer1..6: 32KB each].
// Fragment = 1KB: lane (hi*32+l31) holds n = base_n + l31, k = kk*16 + hi*8 + e.
// Within a layer, frag index = (c*4+kk)*2 + ft  (ft = which 32-neuron half).
#define NG_STRIDE 204800
#define WS_WOUT   819200                 // layer7: 16 kk x 1 frag = 16KB
#define WS_TOTAL  (WS_WOUT + 16384)

typedef short bf16x8 __attribute__((ext_vector_type(8)));
typedef float f32x16 __attribute__((ext_vector_type(16)));
typedef float f32x4v __attribute__((ext_vector_type(4)));

__device__ __forceinline__ unsigned short f2bf(float f) {
    union { float f; unsigned int u; } v; v.f = f;
    unsigned int u = v.u;
    u += 0x7fffu + ((u >> 16) & 1u);   // round-to-nearest-even
    return (unsigned short)(u >> 16);
}
__device__ __forceinline__ unsigned int cvt_pk_bf16(float lo, float hi) {
    unsigned int d;
    asm("v_cvt_pk_bf16_f32 %0, %1, %2" : "=v"(d) : "v"(lo), "v"(hi));
    return d;
}

// ---------------------------------------------------------------------------
// prep: fp32 weights -> bf16 MFMA A-fragment streams in ws
// ---------------------------------------------------------------------------
__global__ void prep_kernel(const float* __restrict__ W_in,
                            const float* __restrict__ W_hid,
                            const float* __restrict__ W_out,
                            unsigned char* __restrict__ ws) {
    int id = blockIdx.x * 256 + threadIdx.x;
    if (id < 16384) {                        // W_in: k(64 pad) x n(256)
        int n = id & 255, k = id >> 8;
        int ng = n >> 6, ft = (n >> 5) & 1, ln = n & 31;
        int kk = k >> 4, hi = (k >> 3) & 1, e = k & 7;
        float v = (k < 40) ? W_in[k * 256 + n] : 0.f;
        *(unsigned short*)(ws + ng * NG_STRIDE + (kk * 2 + ft) * 1024
                           + (hi * 32 + ln) * 16 + e * 2) = f2bf(v);
    } else if (id < 16384 + 393216) {        // W_hid: 6 x k(256) x n(256)
        int e2 = id - 16384;
        int l = e2 >> 16, r = e2 & 65535;
        int k = r >> 8, n = r & 255;
        int c = k >> 6, kk = (k >> 4) & 3, hi = (k >> 3) & 1, e = k & 7;
        int ng = n >> 6, ft = (n >> 5) & 1, ln = n & 31;
        float v = W_hid[l * 65536 + k * 256 + n];
        *(unsigned short*)(ws + ng * NG_STRIDE + 8192 + l * 32768
                           + ((c * 4 + kk) * 2 + ft) * 1024
                           + (hi * 32 + ln) * 16 + e * 2) = f2bf(v);
    } else if (id < 16384 + 393216 + 8192) { // W_out: k(256) x n(3 -> 32 pad)
        int e3 = id - 16384 - 393216;
        int n = e3 >> 8, k = e3 & 255;
        int kk = k >> 4, hi = (k >> 3) & 1, e = k & 7;
        float v = (n < 3) ? W_out[k * 3 + n] : 0.f;
        *(unsigned short*)(ws + WS_WOUT + kk * 1024
                           + (hi * 32 + n) * 16 + e * 2) = f2bf(v);
    }
}

// ---------------------------------------------------------------------------
// one layer: acc = bias; acc += Wt(global frags) x act(LDS); relu; write act
// ---------------------------------------------------------------------------
template <int NC>
__device__ __forceinline__ void layer_pass(const unsigned char* __restrict__ wl,
                                           const float* __restrict__ bp,
                                           unsigned char* actL, f32x16 (&acc)[2][2],
                                           int nblk, int rblk, int l31,
                                           int hi, int hi16, int swz) {
    // bias -> accumulator init (C/D layout: n = (reg&3) + 8*(reg>>2) + 4*hi)
    #pragma unroll
    for (int tn = 0; tn < 2; ++tn) {
        #pragma unroll
        for (int g4 = 0; g4 < 4; ++g4) {
            f32x4v bv = *(const f32x4v*)(bp + nblk + tn * 32 + g4 * 8 + hi * 4);
            #pragma unroll
            for (int j = 0; j < 4; ++j) {
                acc[tn][0][g4 * 4 + j] = bv[j];
                acc[tn][1][g4 * 4 + j] = bv[j];
            }
        }
    }
    const unsigned char* br0 = actL + (rblk      + l31) * 512;
    const unsigned char* br1 = actL + (rblk + 32 + l31) * 512;
    int io[4];
    #pragma unroll
    for (int kk = 0; kk < 4; ++kk) io[kk] = (kk * 32 + hi16) ^ swz;

    __builtin_amdgcn_s_setprio(1);
    #pragma unroll
    for (int c = 0; c < NC; ++c) {
        #pragma unroll
        for (int kk = 0; kk < 4; ++kk) {
            const unsigned char* fp = wl + (c * 4 + kk) * 2048;
            bf16x8 a0 = *(const bf16x8*)(fp);
            bf16x8 a1 = *(const bf16x8*)(fp + 1024);
            bf16x8 b0 = *(const bf16x8*)(br0 + c * 128 + io[kk]);
            bf16x8 b1 = *(const bf16x8*)(br1 + c * 128 + io[kk]);
            acc[0][0] = __builtin_amdgcn_mfma_f32_32x32x16_bf16(a0, b0, acc[0][0], 0, 0, 0);
            acc[1][0] = __builtin_amdgcn_mfma_f32_32x32x16_bf16(a1, b0, acc[1][0], 0, 0, 0);
            acc[0][1] = __builtin_amdgcn_mfma_f32_32x32x16_bf16(a0, b1, acc[0][1], 0, 0, 0);
            acc[1][1] = __builtin_amdgcn_mfma_f32_32x32x16_bf16(a1, b1, acc[1][1], 0, 0, 0);
        }
    }
    __builtin_amdgcn_s_setprio(0);

    __syncthreads();   // all waves done READING act
    #pragma unroll
    for (int tr = 0; tr < 2; ++tr) {
        unsigned char* rowp = actL + (rblk + tr * 32 + l31) * 512;
        #pragma unroll
        for (int tn = 0; tn < 2; ++tn) {
            #pragma unroll
            for (int g4 = 0; g4 < 4; ++g4) {
                float v0 = fmaxf(acc[tn][tr][g4 * 4 + 0], 0.f);
                float v1 = fmaxf(acc[tn][tr][g4 * 4 + 1], 0.f);
                float v2 = fmaxf(acc[tn][tr][g4 * 4 + 2], 0.f);
                float v3 = fmaxf(acc[tn][tr][g4 * 4 + 3], 0.f);
                int n0b = (nblk + tn * 32 + g4 * 8 + hi * 4) * 2;
                uint2 u; u.x = cvt_pk_bf16(v0, v1); u.y = cvt_pk_bf16(v2, v3);
                *(uint2*)(rowp + (n0b ^ swz)) = u;
            }
        }
    }
    __syncthreads();   // act ready for next layer
}

// ---------------------------------------------------------------------------
// fused MLP: enc -> 7x(GEMM+bias+relu), act in LDS, weights global->reg
// ---------------------------------------------------------------------------
__global__ __launch_bounds__(THREADS, 4)
void nerf_main(const float* __restrict__ x,
               const float* __restrict__ b_in,
               const float* __restrict__ b_hid,
               const float* __restrict__ b_out,
               const unsigned char* __restrict__ ws,
               float* __restrict__ out) {
    __shared__ __align__(16) unsigned char actL[65536];  // bf16 [128][256]

    const int tid  = threadIdx.x;
    const int lane = tid & 63;
    const int wv   = tid >> 6;            // 0..7
    const int l31  = lane & 31;
    const int hi   = lane >> 5;
    const int hi16 = hi << 4;
    const int swz  = (l31 & 7) << 4;      // XOR bank swizzle
    const int ng   = wv & 3,  nblk = ng * 64;
    const int rg   = wv >> 2, rblk = rg * 64;
    const long gr0 = (long)blockIdx.x * BR;

    // ---- positional encoding into act LDS (k 0..39, zeros 40..63) ----
    {
        const int rr = tid >> 2, part = tid & 3;
        const int co = part >> 1, hf = part & 1;
        float xv = x[(gr0 + rr) * 2 + co];
        unsigned char* rowp = actL + rr * 512;
        const int rsw = (rr & 7) << 4;
        const int kb = co * 20 + hf * 10;
        float vv[10];
        #pragma unroll
        for (int f = 0; f < 10; ++f) {
            float ang = xv * (float)(1 << f);
            vv[f] = hf ? __cosf(ang) : __sinf(ang);
        }
        #pragma unroll
        for (int p = 0; p < 5; ++p) {
            unsigned int u = cvt_pk_bf16(vv[2 * p], vv[2 * p + 1]);
            int byte = (kb + 2 * p) * 2;
            *(unsigned int*)(rowp + (byte ^ rsw)) = u;
        }
        int z = 80 + part * 12;           // zero-pad bytes [80,128)
        *(unsigned int*)(rowp + ((z    ) ^ rsw)) = 0u;
        *(unsigned int*)(rowp + ((z + 4) ^ rsw)) = 0u;
        *(unsigned int*)(rowp + ((z + 8) ^ rsw)) = 0u;
    }
    __syncthreads();

    f32x16 acc[2][2];
    const unsigned char* wstream = ws + ng * NG_STRIDE + lane * 16;

    // layer 0 (k=64, 1 chunk)
    layer_pass<1>(wstream, b_in, actL, acc, nblk, rblk, l31, hi, hi16, swz);
    wstream += 8192;

    // layers 1..6
    #pragma unroll 1
    for (int l = 0; l < 6; ++l) {
        layer_pass<4>(wstream, b_hid + l * 256,
                      actL, acc, nblk, rblk, l31, hi, hi16, swz);
        wstream += 32768;
    }

    // ---- layer 7: [128][256] @ Wt_out[32pad][256] -> tanh/100 -> out ----
    if (wv < 4) {
        f32x16 c0, c1;
        #pragma unroll
        for (int j = 0; j < 16; ++j) { c0[j] = 0.f; c1[j] = 0.f; }
        const unsigned char* wo   = ws + WS_WOUT + lane * 16;
        const unsigned char* arow = actL + (wv * 32 + l31) * 512;
        #pragma unroll
        for (int kk = 0; kk < 16; ++kk) {
            bf16x8 a = *(const bf16x8*)(wo + kk * 1024);
            bf16x8 b = *(const bf16x8*)(arow + (((kk * 32 + hi16)) ^ swz));
            if (kk & 1) c1 = __builtin_amdgcn_mfma_f32_32x32x16_bf16(a, b, c1, 0, 0, 0);
            else        c0 = __builtin_amdgcn_mfma_f32_32x32x16_bf16(a, b, c0, 0, 0, 0);
        }
        if (hi == 0) {
            long row = gr0 + wv * 32 + l31;
            float* op = out + row * 3;
            #pragma unroll
            for (int j = 0; j < 3; ++j)
                op[j] = tanhf(c0[j] + c1[j] + b_out[j]) * 0.01f;
        }
    }
}

extern "C" void kernel_launch(void* const* d_in, const int* in_sizes, int n_in,
                              void* d_out, int out_size, void* d_ws, size_t ws_size,
                              hipStream_t stream) {
    (void)in_sizes; (void)n_in; (void)out_size;
    const float* x     = (const float*)d_in[0];
    const float* W_in  = (const float*)d_in[1];
    const float* b_in  = (const float*)d_in[2];
    const float* W_hid = (const float*)d_in[3];
    const float* b_hid = (const float*)d_in[4];
    const float* W_out = (const float*)d_in[5];
    const float* b_out = (const float*)d_in[6];
    unsigned char* ws  = (unsigned char*)d_ws;
    float* out = (float*)d_out;

    if (ws_size < (size_t)WS_TOTAL) return;

    prep_kernel<<<1632, 256, 0, stream>>>(W_in, W_hid, W_out, ws);
    nerf_main<<<NBLOCKS, THREADS, 0, stream>>>(x, b_in, b_hid, b_out, ws, out);
}

// Round 5
// 731.240 us; speedup vs baseline: 1.5380x; 1.1193x over previous
//
#include <hip/hip_runtime.h>
#include <stdint.h>

#define THREADS 256
#define NBLOCKS 8192
#define BR      128

// d_ws layout: bf16 weights as MFMA A-fragments, CONTIGUOUS per wave (ng).
// Per-ng stream (200KB): [layer0: 8KB][layer1..6: 32KB each].
// Fragment = 1KB: lane (hi*32+l31) holds n = base_n + l31, k = kk*16 + hi*8 + e.
// Within a layer, frag index = (c*4+kk)*2 + ft  (ft = which 32-neuron half).
#define NG_STRIDE 204800
#define WS_WOUT   819200                 // layer7: 16 kk x 1 frag = 16KB
#define WS_TOTAL  (WS_WOUT + 16384)

typedef short bf16x8 __attribute__((ext_vector_type(8)));
typedef float f32x16 __attribute__((ext_vector_type(16)));
typedef float f32x4v __attribute__((ext_vector_type(4)));

__device__ __forceinline__ unsigned short f2bf(float f) {
    union { float f; unsigned int u; } v; v.f = f;
    unsigned int u = v.u;
    u += 0x7fffu + ((u >> 16) & 1u);   // round-to-nearest-even
    return (unsigned short)(u >> 16);
}
__device__ __forceinline__ unsigned int cvt_pk_bf16(float lo, float hi) {
    unsigned int d;
    asm("v_cvt_pk_bf16_f32 %0, %1, %2" : "=v"(d) : "v"(lo), "v"(hi));
    return d;
}

// ---------------------------------------------------------------------------
// prep: fp32 weights -> bf16 MFMA A-fragment streams in ws (same as R3)
// ---------------------------------------------------------------------------
__global__ void prep_kernel(const float* __restrict__ W_in,
                            const float* __restrict__ W_hid,
                            const float* __restrict__ W_out,
                            unsigned char* __restrict__ ws) {
    int id = blockIdx.x * 256 + threadIdx.x;
    if (id < 16384) {                        // W_in: k(64 pad) x n(256)
        int n = id & 255, k = id >> 8;
        int ng = n >> 6, ft = (n >> 5) & 1, ln = n & 31;
        int kk = k >> 4, hi = (k >> 3) & 1, e = k & 7;
        float v = (k < 40) ? W_in[k * 256 + n] : 0.f;
        *(unsigned short*)(ws + ng * NG_STRIDE + (kk * 2 + ft) * 1024
                           + (hi * 32 + ln) * 16 + e * 2) = f2bf(v);
    } else if (id < 16384 + 393216) {        // W_hid: 6 x k(256) x n(256)
        int e2 = id - 16384;
        int l = e2 >> 16, r = e2 & 65535;
        int k = r >> 8, n = r & 255;
        int c = k >> 6, kk = (k >> 4) & 3, hi = (k >> 3) & 1, e = k & 7;
        int ng = n >> 6, ft = (n >> 5) & 1, ln = n & 31;
        float v = W_hid[l * 65536 + k * 256 + n];
        *(unsigned short*)(ws + ng * NG_STRIDE + 8192 + l * 32768
                           + ((c * 4 + kk) * 2 + ft) * 1024
                           + (hi * 32 + ln) * 16 + e * 2) = f2bf(v);
    } else if (id < 16384 + 393216 + 8192) { // W_out: k(256) x n(3 -> 32 pad)
        int e3 = id - 16384 - 393216;
        int n = e3 >> 8, k = e3 & 255;
        int kk = k >> 4, hi = (k >> 3) & 1, e = k & 7;
        float v = (n < 3) ? W_out[k * 3 + n] : 0.f;
        *(unsigned short*)(ws + WS_WOUT + kk * 1024
                           + (hi * 32 + n) * 16 + e * 2) = f2bf(v);
    }
}

// ---------------------------------------------------------------------------
// one layer: wave = 64n x 128r. A from global, B from LDS, compiler-scheduled
// (R3-proven body structure; acc widened to [2][4]).
// ---------------------------------------------------------------------------
template <int NC>
__device__ __forceinline__ void layer_pass(const unsigned char* __restrict__ wl,
                                           const float* __restrict__ bp,
                                           unsigned char* actL, f32x16 (&acc)[2][4],
                                           int nblk, int l31,
                                           int hi, int hi16, int swz) {
    // bias -> accumulator init (C/D layout: n = (reg&3) + 8*(reg>>2) + 4*hi)
    #pragma unroll
    for (int tn = 0; tn < 2; ++tn) {
        #pragma unroll
        for (int g4 = 0; g4 < 4; ++g4) {
            f32x4v bv = *(const f32x4v*)(bp + nblk + tn * 32 + g4 * 8 + hi * 4);
            #pragma unroll
            for (int tr = 0; tr < 4; ++tr) {
                #pragma unroll
                for (int j = 0; j < 4; ++j)
                    acc[tn][tr][g4 * 4 + j] = bv[j];
            }
        }
    }

    int io[4];
    #pragma unroll
    for (int kk = 0; kk < 4; ++kk) io[kk] = (kk * 32 + hi16) ^ swz;

    __builtin_amdgcn_s_setprio(1);
    #pragma unroll
    for (int c = 0; c < NC; ++c) {
        #pragma unroll
        for (int kk = 0; kk < 4; ++kk) {
            const unsigned char* fp = wl + (c * 4 + kk) * 2048;
            bf16x8 a0 = *(const bf16x8*)(fp);
            bf16x8 a1 = *(const bf16x8*)(fp + 1024);
            const int bo = c * 128 + io[kk];
            bf16x8 b0 = *(const bf16x8*)(actL + (      l31) * 512 + bo);
            bf16x8 b1 = *(const bf16x8*)(actL + (32  + l31) * 512 + bo);
            bf16x8 b2 = *(const bf16x8*)(actL + (64  + l31) * 512 + bo);
            bf16x8 b3 = *(const bf16x8*)(actL + (96  + l31) * 512 + bo);
            acc[0][0] = __builtin_amdgcn_mfma_f32_32x32x16_bf16(a0, b0, acc[0][0], 0, 0, 0);
            acc[1][0] = __builtin_amdgcn_mfma_f32_32x32x16_bf16(a1, b0, acc[1][0], 0, 0, 0);
            acc[0][1] = __builtin_amdgcn_mfma_f32_32x32x16_bf16(a0, b1, acc[0][1], 0, 0, 0);
            acc[1][1] = __builtin_amdgcn_mfma_f32_32x32x16_bf16(a1, b1, acc[1][1], 0, 0, 0);
            acc[0][2] = __builtin_amdgcn_mfma_f32_32x32x16_bf16(a0, b2, acc[0][2], 0, 0, 0);
            acc[1][2] = __builtin_amdgcn_mfma_f32_32x32x16_bf16(a1, b2, acc[1][2], 0, 0, 0);
            acc[0][3] = __builtin_amdgcn_mfma_f32_32x32x16_bf16(a0, b3, acc[0][3], 0, 0, 0);
            acc[1][3] = __builtin_amdgcn_mfma_f32_32x32x16_bf16(a1, b3, acc[1][3], 0, 0, 0);
        }
    }
    __builtin_amdgcn_s_setprio(0);

    __syncthreads();   // all waves done READING act
    #pragma unroll
    for (int tr = 0; tr < 4; ++tr) {
        unsigned char* rowp = actL + (tr * 32 + l31) * 512;
        #pragma unroll
        for (int tn = 0; tn < 2; ++tn) {
            #pragma unroll
            for (int g4 = 0; g4 < 4; ++g4) {
                float v0 = fmaxf(acc[tn][tr][g4 * 4 + 0], 0.f);
                float v1 = fmaxf(acc[tn][tr][g4 * 4 + 1], 0.f);
                float v2 = fmaxf(acc[tn][tr][g4 * 4 + 2], 0.f);
                float v3 = fmaxf(acc[tn][tr][g4 * 4 + 3], 0.f);
                int n0b = (nblk + tn * 32 + g4 * 8 + hi * 4) * 2;
                uint2 u; u.x = cvt_pk_bf16(v0, v1); u.y = cvt_pk_bf16(v2, v3);
                *(uint2*)(rowp + (n0b ^ swz)) = u;
            }
        }
    }
    __syncthreads();   // act ready for next layer
}

// ---------------------------------------------------------------------------
// fused MLP: enc -> 7x(GEMM+bias+relu), act in LDS, weights global->reg
// ---------------------------------------------------------------------------
__global__ __launch_bounds__(THREADS, 2)
void nerf_main(const float* __restrict__ x,
               const float* __restrict__ b_in,
               const float* __restrict__ b_hid,
               const float* __restrict__ b_out,
               const unsigned char* __restrict__ ws,
               float* __restrict__ out) {
    __shared__ __align__(16) unsigned char actL[65536];  // bf16 [128][256]

    const int tid  = threadIdx.x;
    const int lane = tid & 63;
    const int wv   = tid >> 6;            // 0..3 (= ng)
    const int l31  = lane & 31;
    const int hi   = lane >> 5;
    const int hi16 = hi << 4;
    const int swz  = (l31 & 7) << 4;      // XOR bank swizzle
    const int nblk = wv * 64;
    const long gr0 = (long)blockIdx.x * BR;

    // ---- positional encoding (exact R3 body, 2 passes of 64 rows) ----
    #pragma unroll
    for (int pass = 0; pass < 2; ++pass) {
        const int rr = (tid >> 2) + pass * 64;   // 0..127
        const int part = tid & 3;
        const int co = part >> 1, hf = part & 1;
        float xv = x[(gr0 + rr) * 2 + co];
        unsigned char* rowp = actL + rr * 512;
        const int rsw = (rr & 7) << 4;
        const int kb = co * 20 + hf * 10;
        float vv[10];
        #pragma unroll
        for (int f = 0; f < 10; ++f) {
            float ang = xv * (float)(1 << f);
            vv[f] = hf ? __cosf(ang) : __sinf(ang);
        }
        #pragma unroll
        for (int p = 0; p < 5; ++p) {
            unsigned int u = cvt_pk_bf16(vv[2 * p], vv[2 * p + 1]);
            int byte = (kb + 2 * p) * 2;
            *(unsigned int*)(rowp + (byte ^ rsw)) = u;
        }
        int z = 80 + part * 12;           // zero-pad bytes [80,128)
        *(unsigned int*)(rowp + ((z    ) ^ rsw)) = 0u;
        *(unsigned int*)(rowp + ((z + 4) ^ rsw)) = 0u;
        *(unsigned int*)(rowp + ((z + 8) ^ rsw)) = 0u;
    }
    __syncthreads();

    f32x16 acc[2][4];
    const unsigned char* wstream = ws + wv * NG_STRIDE + lane * 16;

    // layer 0 (k=64, 1 chunk)
    layer_pass<1>(wstream, b_in, actL, acc, nblk, l31, hi, hi16, swz);
    wstream += 8192;

    // layers 1..6
    #pragma unroll 1
    for (int l = 0; l < 6; ++l) {
        layer_pass<4>(wstream, b_hid + l * 256,
                      actL, acc, nblk, l31, hi, hi16, swz);
        wstream += 32768;
    }

    // ---- layer 7: [128][256] @ Wt_out[32pad][256] -> tanh/100 -> out ----
    {
        f32x16 c0, c1;
        #pragma unroll
        for (int j = 0; j < 16; ++j) { c0[j] = 0.f; c1[j] = 0.f; }
        const unsigned char* wo   = ws + WS_WOUT + lane * 16;
        const unsigned char* arow = actL + (wv * 32 + l31) * 512;
        #pragma unroll
        for (int kk = 0; kk < 16; ++kk) {
            bf16x8 a = *(const bf16x8*)(wo + kk * 1024);
            bf16x8 b = *(const bf16x8*)(arow + (((kk * 32 + hi16)) ^ swz));
            if (kk & 1) c1 = __builtin_amdgcn_mfma_f32_32x32x16_bf16(a, b, c1, 0, 0, 0);
            else        c0 = __builtin_amdgcn_mfma_f32_32x32x16_bf16(a, b, c0, 0, 0, 0);
        }
        if (hi == 0) {
            long row = gr0 + wv * 32 + l31;
            float* op = out + row * 3;
            #pragma unroll
            for (int j = 0; j < 3; ++j)
                op[j] = tanhf(c0[j] + c1[j] + b_out[j]) * 0.01f;
        }
    }
}

extern "C" void kernel_launch(void* const* d_in, const int* in_sizes, int n_in,
                              void* d_out, int out_size, void* d_ws, size_t ws_size,
                              hipStream_t stream) {
    (void)in_sizes; (void)n_in; (void)out_size;
    const float* x     = (const float*)d_in[0];
    const float* W_in  = (const float*)d_in[1];
    const float* b_in  = (const float*)d_in[2];
    const float* W_hid = (const float*)d_in[3];
    const float* b_hid = (const float*)d_in[4];
    const float* W_out = (const float*)d_in[5];
    const float* b_out = (const float*)d_in[6];
    unsigned char* ws  = (unsigned char*)d_ws;
    float* out = (float*)d_out;

    if (ws_size < (size_t)WS_TOTAL) return;

    prep_kernel<<<1632, 256, 0, stream>>>(W_in, W_hid, W_out, ws);
    nerf_main<<<NBLOCKS, THREADS, 0, stream>>>(x, b_in, b_hid, b_out, ws, out);
}